// Round 10
// baseline (5823.294 us; speedup 1.0000x reference)
//
#include <hip/hip_runtime.h>
#include <cstdint>

// ============================================================================
// RBM_BB block Gibbs, bit-exact (recipe frozen, R3/R5/R6/R7-verified):
//   keys   : partitionable threefry; fold-like split key_i = threefry(parent,0,i)
//   bits   : w0 ^ w1 of threefry(key, 0, flat_index); u = (bits>>9|1.0f)-1
//   sample : u < p
//   sigmoid: 1/(1+cephes_expf(-pre)), noFMA Horner, trailing max(res,x)
//   dot    : f32 sequential ascending-k, folded at kc=320 panel boundaries
// R10 perf: scalar v_fma (R9's v_pk_fma_f32 ran on the DP pipe — 1.6x SLOWER,
// reverted). Ping-pong double-buffered LDS, ONE barrier per K-tile; next
// tile's global loads issued after the barrier so they overlap compute.
// Stride-34 pads (2-way max bank aliasing = free). FMA order identical to R7.
// ============================================================================

#define TF_ROT(x, r) (((x) << (r)) | ((x) >> (32 - (r))))

__host__ __device__ __forceinline__ void threefry2x32(
    uint32_t k0, uint32_t k1, uint32_t x0, uint32_t x1,
    uint32_t &o0, uint32_t &o1) {
  const uint32_t ks2 = k0 ^ k1 ^ 0x1BD11BDAu;
  x0 += k0; x1 += k1;
#define TF_R(r) { x0 += x1; x1 = TF_ROT(x1, r); x1 ^= x0; }
  TF_R(13) TF_R(15) TF_R(26) TF_R(6)
  x0 += k1; x1 += ks2 + 1u;
  TF_R(17) TF_R(29) TF_R(16) TF_R(24)
  x0 += ks2; x1 += k0 + 2u;
  TF_R(13) TF_R(15) TF_R(26) TF_R(6)
  x0 += k0; x1 += k1 + 3u;
  TF_R(17) TF_R(29) TF_R(16) TF_R(24)
  x0 += k1; x1 += ks2 + 4u;
  TF_R(13) TF_R(15) TF_R(26) TF_R(6)
  x0 += ks2; x1 += k0 + 5u;
#undef TF_R
  o0 = x0; o1 = x1;
}

// Cephes expf, noFMA (verified in-chain).
__device__ __forceinline__ float cephes_expf(float xin) {
  float xc = fminf(xin, 88.3762626647950f);
  xc = fmaxf(xc, -88.3762626647949f);
  float fx = floorf(xc * 1.44269504088896341f + 0.5f);
  float tmp = 0.693359375f * fx;
  float z2  = -2.12194440e-4f * fx;
  float x = xc - tmp;
  x = x - z2;
  float z = x * x;
  float y = 1.9875691500E-4f * x + 1.3981999507E-3f;
  y = y * x + 8.3334519073E-3f;
  y = y * x + 4.1665795894E-2f;
  y = y * x + 1.6666665459E-1f;
  y = y * x + 5.0000001201E-1f;
  y = y * z + x;
  y = 1.0f + y;
  int n = (int)fx;
  float p2n = __uint_as_float((uint32_t)(n + 127) << 23);
  return fmaxf(y * p2n, xin);
}

__device__ __forceinline__ void sample_store(
    float tot, const float* bias, float* out,
    long b, int ng, int N_total, uint32_t k0, uint32_t k1) {
  float pre = tot + bias[ng];
  float p   = 1.0f / (1.0f + cephes_expf(-pre));
  uint32_t flat = (uint32_t)(b * N_total + ng);
  uint32_t w0, w1;
  threefry2x32(k0, k1, 0u, flat, w0, w1);
  uint32_t bits = w0 ^ w1;
  float u = __uint_as_float((bits >> 9) | 0x3f800000u) - 1.0f;
  out[(long)b * N_total + ng] = (u < p) ? 1.0f : 0.0f;
}

#define AST 34   // A tile [64 m][32 k] + 2 pad
#define BST 34   // B tile [128 n][32 k] + 2 pad

// ----------------------------------------------------------------------------
// GEMM, 64x128 tile, BK=32, 4x8 per thread, double-buffered LDS
// (one __syncthreads per K-tile; next tile's global loads overlap compute).
// SAMPLE=1: full K, fused sigmoid+threefry epilogue.
// SAMPLE=0: split-K partial over panel [z*320, min(K, z*320+320)).
// SINGLE_PANEL=1: no tot[] (K-range within one Eigen panel).
// ----------------------------------------------------------------------------
template <bool SAMPLE, bool SINGLE_PANEL>
__global__ __launch_bounds__(256, 4) void gemm_tile(
    const float* __restrict__ A,     // [Mtot, ldA] row-major
    const float* __restrict__ Bt,    // [N_total, ldA] row-major
    const float* __restrict__ bias,  // [N_total] (SAMPLE only)
    float* __restrict__ out,
    int ldA, int N_total, int K, int tiles_per_panel, int Mtot,
    uint32_t k0, uint32_t k1)
{
  __shared__ float As[2][64 * AST];
  __shared__ float Bs[2][128 * BST];
  const int t  = threadIdx.x;
  const int tx = t & 15;
  const int ty = t >> 4;
  const int bm = blockIdx.x;
  const int j0 = blockIdx.y << 7;

  int kb, ke;
  float* outp = out;
  if (SAMPLE) { kb = 0; ke = K; }
  else {
    const int z = blockIdx.z;
    kb = z * 320;
    ke = min(K, kb + 320);
    outp = out + (size_t)z * Mtot * 128;
  }

  float cur[4][8];
  float tot[4][8];
#pragma unroll
  for (int i = 0; i < 4; ++i)
#pragma unroll
    for (int j = 0; j < 8; ++j) { cur[i][j] = 0.0f; if (!SINGLE_PANEL) tot[i][j] = 0.0f; }

  const long arow = (long)bm * 64 * ldA;
  const int t0 = kb >> 5, t1 = ke >> 5;

  // staging slot indices (fixed per thread)
  const int am0 = t >> 3,           ac0 = t & 7;          // A slots: t, t+256
  const int am1 = (t + 256) >> 3,   ac1 = ac0;
  const int bn0 = t >> 3,           bc0 = t & 7;          // B slots: t+256r
  // global source pointers per tile: A + arow + m*ldA + kc + 4c

  float4 aReg[2], bReg[4];

  // ---- preload tile t0 into registers ----
  {
    const int kc = t0 << 5;
    aReg[0] = *(const float4*)(A + arow + (long)am0 * ldA + kc + 4 * ac0);
    aReg[1] = *(const float4*)(A + arow + (long)am1 * ldA + kc + 4 * ac1);
#pragma unroll
    for (int r = 0; r < 4; ++r) {
      int q = t + 256 * r;
      int n = q >> 3, c = q & 7;
      bReg[r] = *(const float4*)(Bt + (long)(j0 + n) * ldA + kc + 4 * c);
    }
  }

  int pp = 0;
  for (int tki = t0; tki < t1; ++tki) {
    // ---- write staged regs into LDS buf pp (FULL tiles: 512 + 1024 f4) ----
    *(float4*)(As[pp] + am0 * AST + 4 * ac0) = aReg[0];
    *(float4*)(As[pp] + am1 * AST + 4 * ac1) = aReg[1];
#pragma unroll
    for (int r = 0; r < 4; ++r) {
      int q = t + 256 * r;
      int n = q >> 3, c = q & 7;
      *(float4*)(Bs[pp] + n * BST + 4 * c) = bReg[r];
    }
    __syncthreads();

    // ---- issue next tile's global loads (fly during compute) ----
    if (tki + 1 < t1) {
      const int kc = (tki + 1) << 5;
      aReg[0] = *(const float4*)(A + arow + (long)am0 * ldA + kc + 4 * ac0);
      aReg[1] = *(const float4*)(A + arow + (long)am1 * ldA + kc + 4 * ac1);
#pragma unroll
      for (int r = 0; r < 4; ++r) {
        int q = t + 256 * r;
        int n = q >> 3, c = q & 7;
        bReg[r] = *(const float4*)(Bt + (long)(j0 + n) * ldA + kc + 4 * c);
      }
    }

    // ---- compute from buf pp (immediate-offset ds_reads) ----
    const float* aP = As[pp] + ty * AST;
    const float* bP = Bs[pp] + tx * BST;
#pragma unroll
    for (int c = 0; c < 8; ++c) {
      float4 av[4], bv[8];
#pragma unroll
      for (int i = 0; i < 4; ++i)
        av[i] = *(const float4*)(aP + i * 16 * AST + 4 * c);
#pragma unroll
      for (int j = 0; j < 8; ++j)
        bv[j] = *(const float4*)(bP + j * 16 * BST + 4 * c);
#pragma unroll
      for (int i = 0; i < 4; ++i)
#pragma unroll
        for (int j = 0; j < 8; ++j) {
          cur[i][j] = __fmaf_rn(av[i].x, bv[j].x, cur[i][j]);
          cur[i][j] = __fmaf_rn(av[i].y, bv[j].y, cur[i][j]);
          cur[i][j] = __fmaf_rn(av[i].z, bv[j].z, cur[i][j]);
          cur[i][j] = __fmaf_rn(av[i].w, bv[j].w, cur[i][j]);
        }
    }

    if (!SINGLE_PANEL) {
      if (((tki - t0 + 1) % tiles_per_panel == 0) || (tki == t1 - 1)) {
#pragma unroll
        for (int i = 0; i < 4; ++i)
#pragma unroll
          for (int j = 0; j < 8; ++j) { tot[i][j] += cur[i][j]; cur[i][j] = 0.0f; }
      }
    }
    pp ^= 1;
  }

#pragma unroll
  for (int i = 0; i < 4; ++i) {
    const int m = ty + 16 * i;
    const long b = (long)bm * 64 + m;
#pragma unroll
    for (int j = 0; j < 8; ++j) {
      const int n  = tx + 16 * j;
      const int ng = j0 + n;
      const float v = SINGLE_PANEL ? cur[i][j] : tot[i][j];
      if (SAMPLE) {
        sample_store(v, bias, outp, b, ng, N_total, k0, k1);
      } else {
        outp[b * 128 + ng] = v;   // raw panel partial (j0==0, N_total==128)
      }
    }
  }
}

// Fold 4 panel partials in exact order, then bias+sigmoid+sample.
__global__ __launch_bounds__(256) void combine_sample(
    const float* __restrict__ partials,  // [4][Mtot*128]
    const float* __restrict__ bias,      // [128]
    float* __restrict__ out,             // [Mtot*128] binary f32
    int Mtot, uint32_t k0, uint32_t k1)
{
  const long idx = (long)blockIdx.x * 256 + threadIdx.x;
  const long S = (long)Mtot * 128;
  float p0 = partials[idx];
  float p1 = partials[S + idx];
  float p2 = partials[2 * S + idx];
  float p3 = partials[3 * S + idx];
  float tot = ((p0 + p1) + p2) + p3;          // Eigen fold order, exact
  float pre = tot + bias[(int)(idx & 127)];
  float p   = 1.0f / (1.0f + cephes_expf(-pre));
  uint32_t w0, w1;
  threefry2x32(k0, k1, 0u, (uint32_t)idx, w0, w1);
  uint32_t bits = w0 ^ w1;
  float u = __uint_as_float((bits >> 9) | 0x3f800000u) - 1.0f;
  out[idx] = (u < p) ? 1.0f : 0.0f;
}

__global__ void transpose_W(const float* __restrict__ W, float* __restrict__ Wt) {
  __shared__ float tile[32][33];
  int bx = blockIdx.x, by = blockIdx.y;
  int x = threadIdx.x, y = threadIdx.y;
  tile[y][x] = W[(by * 32 + y) * 1024 + bx * 32 + x];
  __syncthreads();
  Wt[(bx * 32 + y) * 128 + by * 32 + x] = tile[x][y];
}

extern "C" void kernel_launch(void* const* d_in, const int* in_sizes, int n_in,
                              void* d_out, int out_size, void* d_ws, size_t ws_size,
                              hipStream_t stream) {
  const float* v0 = (const float*)d_in[0];   // [B,1024]
  const float* W  = (const float*)d_in[1];   // [128,1024]
  const float* bb = (const float*)d_in[2];   // [1024]
  const float* cb = (const float*)d_in[3];   // [128]
  const int B = in_sizes[0] / 1024;          // 32768

  float* out    = (float*)d_out;
  float* out_v  = out;                        // v_given_h   [B,1024]
  float* out_h1 = out + (size_t)B * 1024;     // h_given_v   [B,128]
  float* out_h2 = out_h1 + (size_t)B * 128;   // h_given_v_0 [B,128]

  float* Wt       = (float*)d_ws;                       // [1024,128]
  float* h_ws     = Wt + 1024 * 128;                    // [B,128]
  float* partials = h_ws + (size_t)B * 128;             // [4][B,128]
  const size_t need = (size_t)(1024 * 128 + (size_t)B * 128 * 5) * 4;
  const bool use_split = ws_size >= need;

  // partitionable keys: seed 42, fold-like split
  uint32_t kt[5][2], kv[5][2], kh[5][2];
  for (uint32_t i = 0; i < 5; ++i) threefry2x32(0u, 42u, 0u, i, kt[i][0], kt[i][1]);
  for (int t = 1; t <= 4; ++t) {
    threefry2x32(kt[t][0], kt[t][1], 0u, 0u, kv[t][0], kv[t][1]);
    threefry2x32(kt[t][0], kt[t][1], 0u, 1u, kh[t][0], kh[t][1]);
  }

  transpose_W<<<dim3(32, 4), dim3(32, 32), 0, stream>>>(W, Wt);

  const int MB = B / 64;     // 512 row-blocks

  // h-step: hdst = bernoulli(key, sigmoid(W vin + c))
  auto h_step = [&](const float* vin, float* hdst, uint32_t hk0, uint32_t hk1) {
    if (use_split) {
      gemm_tile<false, true><<<dim3(MB, 1, 4), 256, 0, stream>>>(
          vin, W, nullptr, partials, 1024, 128, 1024, 1000, B, 0u, 0u);
      combine_sample<<<dim3(B * 128 / 256), 256, 0, stream>>>(
          partials, cb, hdst, B, hk0, hk1);
    } else {
      gemm_tile<true, false><<<dim3(MB, 1, 1), 256, 0, stream>>>(
          vin, W, cb, hdst, 1024, 128, 1024, 10, B, hk0, hk1);
    }
  };

  // h0 = bernoulli(kt[0], sigmoid(W v0 + c))
  h_step(v0, out_h2, kt[0][0], kt[0][1]);

  const float* h = out_h2;
  for (int t = 1; t <= 4; ++t) {
    // v_t = bernoulli(kv[t], sigmoid(W^T h + b)) — K=128, single panel
    gemm_tile<true, true><<<dim3(MB, 8, 1), 256, 0, stream>>>(
        h, Wt, bb, out_v, 128, 1024, 128, 10, B, kv[t][0], kv[t][1]);
    // h_t = bernoulli(kh[t], sigmoid(W v_t + c))
    float* hdst = (t == 4) ? out_h1 : h_ws;
    h_step(out_v, hdst, kh[t][0], kh[t][1]);
    h = hdst;
  }
}

// Round 11
// 1463.841 us; speedup vs baseline: 3.9781x; 3.9781x over previous
//
#include <hip/hip_runtime.h>
#include <cstdint>

// ============================================================================
// RBM_BB block Gibbs, bit-exact (recipe frozen, R3/R5/R6/R7-verified):
//   keys   : partitionable threefry; fold-like split key_i = threefry(parent,0,i)
//   bits   : w0 ^ w1 of threefry(key, 0, flat_index); u = (bits>>9|1.0f)-1
//   sample : u < p
//   sigmoid: 1/(1+cephes_expf(-pre)), noFMA Horner, trailing max(res,x)
//   dot    : f32 sequential ascending-k, folded at kc=320 panel boundaries
// R11 perf: __builtin_amdgcn_global_load_lds staging (no VGPR round-trip, no
// ds_writes — R10's dbuf spilled staging regs to scratch: 301 MB WRITE_SIZE).
// B-tile k-major [32][128] straight from the k-major weight copy (v: W,
// h: Wt), reads float4@4tx = conflict-free unpadded. A-tile [64][32].
// Per-output k-chain and fold order unchanged -> bit-exact.
// ============================================================================

#define TF_ROT(x, r) (((x) << (r)) | ((x) >> (32 - (r))))

__host__ __device__ __forceinline__ void threefry2x32(
    uint32_t k0, uint32_t k1, uint32_t x0, uint32_t x1,
    uint32_t &o0, uint32_t &o1) {
  const uint32_t ks2 = k0 ^ k1 ^ 0x1BD11BDAu;
  x0 += k0; x1 += k1;
#define TF_R(r) { x0 += x1; x1 = TF_ROT(x1, r); x1 ^= x0; }
  TF_R(13) TF_R(15) TF_R(26) TF_R(6)
  x0 += k1; x1 += ks2 + 1u;
  TF_R(17) TF_R(29) TF_R(16) TF_R(24)
  x0 += ks2; x1 += k0 + 2u;
  TF_R(13) TF_R(15) TF_R(26) TF_R(6)
  x0 += k0; x1 += k1 + 3u;
  TF_R(17) TF_R(29) TF_R(16) TF_R(24)
  x0 += k1; x1 += ks2 + 4u;
  TF_R(13) TF_R(15) TF_R(26) TF_R(6)
  x0 += ks2; x1 += k0 + 5u;
#undef TF_R
  o0 = x0; o1 = x1;
}

// Cephes expf, noFMA (verified in-chain).
__device__ __forceinline__ float cephes_expf(float xin) {
  float xc = fminf(xin, 88.3762626647950f);
  xc = fmaxf(xc, -88.3762626647949f);
  float fx = floorf(xc * 1.44269504088896341f + 0.5f);
  float tmp = 0.693359375f * fx;
  float z2  = -2.12194440e-4f * fx;
  float x = xc - tmp;
  x = x - z2;
  float z = x * x;
  float y = 1.9875691500E-4f * x + 1.3981999507E-3f;
  y = y * x + 8.3334519073E-3f;
  y = y * x + 4.1665795894E-2f;
  y = y * x + 1.6666665459E-1f;
  y = y * x + 5.0000001201E-1f;
  y = y * z + x;
  y = 1.0f + y;
  int n = (int)fx;
  float p2n = __uint_as_float((uint32_t)(n + 127) << 23);
  return fmaxf(y * p2n, xin);
}

__device__ __forceinline__ float sample_val(
    float tot, float bias, long b, int ng, int N_total,
    uint32_t k0, uint32_t k1) {
  float pre = tot + bias;
  float p   = 1.0f / (1.0f + cephes_expf(-pre));
  uint32_t flat = (uint32_t)(b * N_total + ng);
  uint32_t w0, w1;
  threefry2x32(k0, k1, 0u, flat, w0, w1);
  uint32_t bits = w0 ^ w1;
  float u = __uint_as_float((bits >> 9) | 0x3f800000u) - 1.0f;
  return (u < p) ? 1.0f : 0.0f;
}

// async global->LDS, 16B per lane; LDS dest = uniform base + lane*16.
__device__ __forceinline__ void gl2lds16(const float* g, float* l) {
  __builtin_amdgcn_global_load_lds(
      (const __attribute__((address_space(1))) void*)g,
      (__attribute__((address_space(3))) void*)l, 16, 0, 0);
}

// ----------------------------------------------------------------------------
// GEMM, 64x128 tile, BK=32. A [Mtot,lda] row-major (k-contig); Bkm [K,ldb]
// k-major (n-contig rows). Per-thread 4 m x 8 n, n = 4*tx + 64*jq + e.
// SAMPLE=1: full K, fused sigmoid+threefry epilogue.
// SAMPLE=0: split-K partial over panel [z*320, min(K, z*320+320)).
// SINGLE_PANEL=1: no tot[] (K-range within one Eigen panel).
// ----------------------------------------------------------------------------
template <bool SAMPLE, bool SINGLE_PANEL>
__global__ __launch_bounds__(256, 5) void gemm_tile(
    const float* __restrict__ A,     // [Mtot, lda]
    const float* __restrict__ Bkm,   // [K, ldb] k-major
    const float* __restrict__ bias,  // [N_total] (SAMPLE only)
    float* __restrict__ out,
    int lda, int ldb, int N_total, int K, int tiles_per_panel, int Mtot,
    uint32_t k0, uint32_t k1)
{
  __shared__ float As[64 * 32];     // [m][k] unpadded (lds-dma layout)
  __shared__ float Bs[32 * 128];    // [k][n] unpadded
  const int t  = threadIdx.x;
  const int tx = t & 15;
  const int ty = t >> 4;
  const int w  = t >> 6;            // wave id
  const int bm = blockIdx.x;
  const int j0 = blockIdx.y << 7;

  int kb, ke;
  float* outp = out;
  if (SAMPLE) { kb = 0; ke = K; }
  else {
    const int z = blockIdx.z;
    kb = z * 320;
    ke = min(K, kb + 320);
    outp = out + (size_t)z * Mtot * 128;
  }

  float cur[4][8];
  float tot[4][8];
#pragma unroll
  for (int i = 0; i < 4; ++i)
#pragma unroll
    for (int j = 0; j < 8; ++j) { cur[i][j] = 0.0f; if (!SINGLE_PANEL) tot[i][j] = 0.0f; }

  const long arow = (long)bm * 64 * lda;
  const int t0 = kb >> 5, t1 = ke >> 5;

  const float* aP = As + ty * 32;
  const float* bP = Bs + 4 * tx;

  for (int tki = t0; tki < t1; ++tki) {
    const int kc = tki << 5;
    __syncthreads();   // protect LDS reuse (prev tile's reads done)
    // ---- A tile: 512 f4 slots, slot = r*256 + t; m=slot>>3, c=slot&7 ----
#pragma unroll
    for (int r = 0; r < 2; ++r) {
      int slot = r * 256 + t;
      int m = slot >> 3, c = slot & 7;
      gl2lds16(A + arow + (long)m * lda + kc + 4 * c,
               As + (r * 256 + w * 64) * 4);
    }
    // ---- B tile k-major: 1024 f4 slots, kk=slot>>5, nc=slot&31 ----
#pragma unroll
    for (int r = 0; r < 4; ++r) {
      int slot = r * 256 + t;
      int kk = slot >> 5, nc = slot & 31;
      gl2lds16(Bkm + (long)(kc + kk) * ldb + j0 + 4 * nc,
               Bs + (r * 256 + w * 64) * 4);
    }
    __syncthreads();   // vmcnt(0) drain: staged data visible

    // ---- compute: k ascending 4c+cc; per k, bv = [4tx..] and [4tx+64..] ----
#pragma unroll
    for (int c = 0; c < 8; ++c) {
      float4 av[4];
#pragma unroll
      for (int i = 0; i < 4; ++i)
        av[i] = *(const float4*)(aP + i * 16 * 32 + 4 * c);
#pragma unroll
      for (int cc = 0; cc < 4; ++cc) {
        const float* brow = bP + (4 * c + cc) * 128;
        float4 b0 = *(const float4*)(brow);
        float4 b1 = *(const float4*)(brow + 64);
#pragma unroll
        for (int i = 0; i < 4; ++i) {
          const float a = ((const float*)&av[i])[cc];
          cur[i][0] = __fmaf_rn(a, b0.x, cur[i][0]);
          cur[i][1] = __fmaf_rn(a, b0.y, cur[i][1]);
          cur[i][2] = __fmaf_rn(a, b0.z, cur[i][2]);
          cur[i][3] = __fmaf_rn(a, b0.w, cur[i][3]);
          cur[i][4] = __fmaf_rn(a, b1.x, cur[i][4]);
          cur[i][5] = __fmaf_rn(a, b1.y, cur[i][5]);
          cur[i][6] = __fmaf_rn(a, b1.z, cur[i][6]);
          cur[i][7] = __fmaf_rn(a, b1.w, cur[i][7]);
        }
      }
    }

    if (!SINGLE_PANEL) {
      if (((tki - t0 + 1) % tiles_per_panel == 0) || (tki == t1 - 1)) {
#pragma unroll
        for (int i = 0; i < 4; ++i)
#pragma unroll
          for (int j = 0; j < 8; ++j) { tot[i][j] += cur[i][j]; cur[i][j] = 0.0f; }
      }
    }
  }

  // ---- epilogue: per (i,jq), 4 consecutive cols -> one float4 store ----
#pragma unroll
  for (int i = 0; i < 4; ++i) {
    const int m = ty + 16 * i;
    const long b = (long)bm * 64 + m;
#pragma unroll
    for (int jq = 0; jq < 2; ++jq) {
      const int n0 = 4 * tx + 64 * jq;
      float4 o;
      const float* acc = SINGLE_PANEL ? cur[i] : tot[i];
      if (SAMPLE) {
        const int ng = j0 + n0;
        o.x = sample_val(acc[4 * jq + 0], bias[ng],     b, ng,     N_total, k0, k1);
        o.y = sample_val(acc[4 * jq + 1], bias[ng + 1], b, ng + 1, N_total, k0, k1);
        o.z = sample_val(acc[4 * jq + 2], bias[ng + 2], b, ng + 2, N_total, k0, k1);
        o.w = sample_val(acc[4 * jq + 3], bias[ng + 3], b, ng + 3, N_total, k0, k1);
        *(float4*)(outp + b * N_total + ng) = o;
      } else {
        o.x = acc[4 * jq + 0]; o.y = acc[4 * jq + 1];
        o.z = acc[4 * jq + 2]; o.w = acc[4 * jq + 3];
        *(float4*)(outp + b * 128 + n0) = o;   // j0==0, N_total==128
      }
    }
  }
}

// Fold 4 panel partials in exact order, then bias+sigmoid+sample.
__global__ __launch_bounds__(256) void combine_sample(
    const float* __restrict__ partials,  // [4][Mtot*128]
    const float* __restrict__ bias,      // [128]
    float* __restrict__ out,             // [Mtot*128] binary f32
    int Mtot, uint32_t k0, uint32_t k1)
{
  const long idx = (long)blockIdx.x * 256 + threadIdx.x;
  const long S = (long)Mtot * 128;
  float p0 = partials[idx];
  float p1 = partials[S + idx];
  float p2 = partials[2 * S + idx];
  float p3 = partials[3 * S + idx];
  float tot = ((p0 + p1) + p2) + p3;          // Eigen fold order, exact
  float pre = tot + bias[(int)(idx & 127)];
  float p   = 1.0f / (1.0f + cephes_expf(-pre));
  uint32_t w0, w1;
  threefry2x32(k0, k1, 0u, (uint32_t)idx, w0, w1);
  uint32_t bits = w0 ^ w1;
  float u = __uint_as_float((bits >> 9) | 0x3f800000u) - 1.0f;
  out[idx] = (u < p) ? 1.0f : 0.0f;
}

__global__ void transpose_W(const float* __restrict__ W, float* __restrict__ Wt) {
  __shared__ float tile[32][33];
  int bx = blockIdx.x, by = blockIdx.y;
  int x = threadIdx.x, y = threadIdx.y;
  tile[y][x] = W[(by * 32 + y) * 1024 + bx * 32 + x];
  __syncthreads();
  Wt[(bx * 32 + y) * 128 + by * 32 + x] = tile[x][y];
}

extern "C" void kernel_launch(void* const* d_in, const int* in_sizes, int n_in,
                              void* d_out, int out_size, void* d_ws, size_t ws_size,
                              hipStream_t stream) {
  const float* v0 = (const float*)d_in[0];   // [B,1024]
  const float* W  = (const float*)d_in[1];   // [128,1024]
  const float* bb = (const float*)d_in[2];   // [1024]
  const float* cb = (const float*)d_in[3];   // [128]
  const int B = in_sizes[0] / 1024;          // 32768

  float* out    = (float*)d_out;
  float* out_v  = out;                        // v_given_h   [B,1024]
  float* out_h1 = out + (size_t)B * 1024;     // h_given_v   [B,128]
  float* out_h2 = out_h1 + (size_t)B * 128;   // h_given_v_0 [B,128]

  float* Wt       = (float*)d_ws;                       // [1024,128] k-major for h-GEMM
  float* h_ws     = Wt + 1024 * 128;                    // [B,128]
  float* partials = h_ws + (size_t)B * 128;             // [4][B,128]
  const size_t need = (size_t)(1024 * 128 + (size_t)B * 128 * 5) * 4;
  const bool use_split = ws_size >= need;

  // partitionable keys: seed 42, fold-like split
  uint32_t kt[5][2], kv[5][2], kh[5][2];
  for (uint32_t i = 0; i < 5; ++i) threefry2x32(0u, 42u, 0u, i, kt[i][0], kt[i][1]);
  for (int t = 1; t <= 4; ++t) {
    threefry2x32(kt[t][0], kt[t][1], 0u, 0u, kv[t][0], kv[t][1]);
    threefry2x32(kt[t][0], kt[t][1], 0u, 1u, kh[t][0], kh[t][1]);
  }

  transpose_W<<<dim3(32, 4), dim3(32, 32), 0, stream>>>(W, Wt);

  const int MB = B / 64;     // 512 row-blocks

  // h-step: hdst = bernoulli(key, sigmoid(W vin + c)); Bkm = Wt (ldb=128)
  auto h_step = [&](const float* vin, float* hdst, uint32_t hk0, uint32_t hk1) {
    if (use_split) {
      gemm_tile<false, true><<<dim3(MB, 1, 4), 256, 0, stream>>>(
          vin, Wt, nullptr, partials, 1024, 128, 128, 1024, 1000, B, 0u, 0u);
      combine_sample<<<dim3(B * 128 / 256), 256, 0, stream>>>(
          partials, cb, hdst, B, hk0, hk1);
    } else {
      gemm_tile<true, false><<<dim3(MB, 1, 1), 256, 0, stream>>>(
          vin, Wt, cb, hdst, 1024, 128, 128, 1024, 10, B, hk0, hk1);
    }
  };

  // h0 = bernoulli(kt[0], sigmoid(W v0 + c))
  h_step(v0, out_h2, kt[0][0], kt[0][1]);

  const float* h = out_h2;
  for (int t = 1; t <= 4; ++t) {
    // v_t = bernoulli(kv[t], sigmoid(W^T h + b)) — K=128, Bkm = W (ldb=1024)
    gemm_tile<true, true><<<dim3(MB, 8, 1), 256, 0, stream>>>(
        h, W, bb, out_v, 128, 1024, 1024, 128, 10, B, kv[t][0], kv[t][1]);
    // h_t = bernoulli(kh[t], sigmoid(W v_t + c))
    float* hdst = (t == 4) ? out_h1 : h_ws;
    h_step(out_v, hdst, kh[t][0], kh[t][1]);
    h = hdst;
  }
}